// Round 1
// baseline (12873.383 us; speedup 1.0000x reference)
//
#include <hip/hip_runtime.h>
#include <hip/hip_bf16.h>
#include <math.h>

#define S_LEN 2048
#define DIM   1024
#define NSTR  4
#define NHEAD 16
#define HDIM  64
#define NCC   24        // 2*N + N*N
#define NEXP  8
#define FF    512
#define VOC   32000
#define EPSV  1e-6f

__device__ __forceinline__ float waveReduceSum(float v) {
  for (int off = 32; off > 0; off >>= 1) v += __shfl_down(v, off, 64);
  return v;
}
__device__ __forceinline__ float waveReduceMax(float v) {
  for (int off = 32; off > 0; off >>= 1) v = fmaxf(v, __shfl_down(v, off, 64));
  return v;
}
__device__ __forceinline__ float siluf(float g) { return g / (1.f + expf(-g)); }

// ---------------------------------------------------------------- embed
__global__ __launch_bounds__(256) void k_embed(const int* __restrict__ ids,
                                               const float* __restrict__ embed,
                                               float* __restrict__ x) {
  int s = blockIdx.x;
  int id = ids[s];
  const float4* er = (const float4*)(embed + (size_t)id * DIM);
  float4* xr = (float4*)(x + (size_t)s * NSTR * DIM);
  for (int i = threadIdx.x; i < DIM / 4; i += 256) {
    float4 v = er[i];
    xr[i] = v; xr[i + 256] = v; xr[i + 512] = v; xr[i + 768] = v;
  }
}

// ------------------------------------------------- hyper-connection weights
// rms(x[s], over 4096) @ W (4096 x NOUT) + b ; tanh gates (+ sinkhorn)
template <int NOUT, bool SINK>
__global__ __launch_bounds__(256) void k_hc(const float* __restrict__ x,
                                            const float* __restrict__ W,
                                            const float* __restrict__ b,
                                            float* __restrict__ pre,
                                            float* __restrict__ post,
                                            float* __restrict__ Mout) {
  int s = blockIdx.x;
  int tid = threadIdx.x, lane = tid & 63, wid = tid >> 6;
  __shared__ __align__(16) float xs[NSTR * DIM];
  __shared__ float wred[4];
  __shared__ float wacc[4][NOUT];
  const float4* xr = (const float4*)(x + (size_t)s * NSTR * DIM);
  float ss = 0.f;
  for (int i = tid; i < NSTR * DIM / 4; i += 256) {
    float4 v = xr[i];
    ((float4*)xs)[i] = v;
    ss += v.x * v.x + v.y * v.y + v.z * v.z + v.w * v.w;
  }
  ss = waveReduceSum(ss);
  if (lane == 0) wred[wid] = ss;
  __syncthreads();
  float rstd = rsqrtf((wred[0] + wred[1] + wred[2] + wred[3]) / (float)(NSTR * DIM) + EPSV);
  float acc[NOUT];
#pragma unroll
  for (int j = 0; j < NOUT; j++) acc[j] = 0.f;
  for (int i = tid; i < NSTR * DIM; i += 256) {
    float xv = xs[i] * rstd;
    const float4* wr = (const float4*)(W + (size_t)i * NOUT);
#pragma unroll
    for (int j4 = 0; j4 < NOUT / 4; j4++) {
      float4 w = wr[j4];
      acc[j4 * 4 + 0] += xv * w.x; acc[j4 * 4 + 1] += xv * w.y;
      acc[j4 * 4 + 2] += xv * w.z; acc[j4 * 4 + 3] += xv * w.w;
    }
  }
#pragma unroll
  for (int j = 0; j < NOUT; j++) {
    float v = waveReduceSum(acc[j]);
    if (lane == 0) wacc[wid][j] = v;
  }
  __syncthreads();
  if (tid == 0) {
    float raw[NOUT];
#pragma unroll
    for (int j = 0; j < NOUT; j++)
      raw[j] = wacc[0][j] + wacc[1][j] + wacc[2][j] + wacc[3][j] + b[j];
    for (int n = 0; n < 4; n++) pre[s * 4 + n] = 1.f + tanhf(raw[n]);
    if (SINK) {
      for (int n = 0; n < 4; n++) post[s * 4 + n] = 1.f + tanhf(raw[4 + n]);
      float Mv[16];
      float mx = -1e30f;
      for (int i = 0; i < 16; i++) {
        float lg = raw[8 + i] + ((i % 5) == 0 ? 1.f : 0.f);  // + eye(4)
        Mv[i] = lg; mx = fmaxf(mx, lg);
      }
      for (int i = 0; i < 16; i++) Mv[i] = expf(Mv[i] - mx);
      for (int it = 0; it < 20; it++) {
        for (int n = 0; n < 4; n++) {
          float rs = Mv[n*4] + Mv[n*4+1] + Mv[n*4+2] + Mv[n*4+3] + EPSV;
          Mv[n*4] /= rs; Mv[n*4+1] /= rs; Mv[n*4+2] /= rs; Mv[n*4+3] /= rs;
        }
        for (int m = 0; m < 4; m++) {
          float cs = Mv[m] + Mv[4+m] + Mv[8+m] + Mv[12+m] + EPSV;
          Mv[m] /= cs; Mv[4+m] /= cs; Mv[8+m] /= cs; Mv[12+m] /= cs;
        }
      }
      for (int i = 0; i < 16; i++) Mout[s * 16 + i] = Mv[i];
    }
  }
}

// ------------------------------------------------- collapse + rms + scale
// out[s,d] = rms_d( sum_n pre[s,n]*x[s,n,d] ) * g[d]
__global__ __launch_bounds__(256) void k_coll(const float* __restrict__ x,
                                              const float* __restrict__ pre,
                                              const float* __restrict__ g,
                                              float* __restrict__ out) {
  int s = blockIdx.x, tid = threadIdx.x, lane = tid & 63, wid = tid >> 6;
  __shared__ float cl[DIM];
  __shared__ float wred[4];
  float p0 = pre[s*4+0], p1 = pre[s*4+1], p2 = pre[s*4+2], p3 = pre[s*4+3];
  const float* xr = x + (size_t)s * NSTR * DIM;
  float ss = 0.f;
  for (int d = tid; d < DIM; d += 256) {
    float c = p0*xr[d] + p1*xr[DIM+d] + p2*xr[2*DIM+d] + p3*xr[3*DIM+d];
    cl[d] = c; ss += c * c;
  }
  ss = waveReduceSum(ss);
  if (lane == 0) wred[wid] = ss;
  __syncthreads();
  float rstd = rsqrtf((wred[0]+wred[1]+wred[2]+wred[3]) / (float)DIM + EPSV);
  for (int d = tid; d < DIM; d += 256)
    out[(size_t)s * DIM + d] = cl[d] * rstd * g[d];
}

// ---------------------------------------------------------------- sgemm
// C[M,Nn] = A[M,Kd] @ B[Kd,Nn], all row-major, dims divisible by tiles.
template <int BM, int BN>
__global__ __launch_bounds__(256) void sgemm(const float* __restrict__ A,
                                             const float* __restrict__ B,
                                             float* __restrict__ C,
                                             int M, int Kd, int Nn) {
  const int BK = 16;
  const int TM = BM / 16, TN = BN / 16;
  __shared__ __align__(16) float As[BK][BM + 4];
  __shared__ __align__(16) float Bs[BK][BN + 4];
  int tid = threadIdx.x;
  int bn = blockIdx.x, bm = blockIdx.y;
  int ty = tid >> 4, tx = tid & 15;
  float acc[TM][TN];
#pragma unroll
  for (int i = 0; i < TM; i++)
#pragma unroll
    for (int j = 0; j < TN; j++) acc[i][j] = 0.f;
  const float* Ab = A + (size_t)bm * BM * Kd;
  const float* Bb = B + (size_t)bn * BN;
  for (int k0 = 0; k0 < Kd; k0 += BK) {
    for (int i = tid; i < BM * BK / 4; i += 256) {
      int row = i >> 2, c4 = (i & 3) * 4;
      float4 v = *(const float4*)(Ab + (size_t)row * Kd + k0 + c4);
      As[c4+0][row] = v.x; As[c4+1][row] = v.y; As[c4+2][row] = v.z; As[c4+3][row] = v.w;
    }
    for (int i = tid; i < BK * BN / 4; i += 256) {
      int row = i / (BN / 4), c4 = (i % (BN / 4)) * 4;
      *(float4*)(&Bs[row][c4]) = *(const float4*)(Bb + (size_t)(k0 + row) * Nn + c4);
    }
    __syncthreads();
#pragma unroll
    for (int kk = 0; kk < BK; kk++) {
      float a[TM], b[TN];
#pragma unroll
      for (int i = 0; i < TM; i++) a[i] = As[kk][ty + i * 16];
#pragma unroll
      for (int j = 0; j < TN; j++) b[j] = Bs[kk][tx + j * 16];
#pragma unroll
      for (int i = 0; i < TM; i++)
#pragma unroll
        for (int j = 0; j < TN; j++) acc[i][j] += a[i] * b[j];
    }
    __syncthreads();
  }
  float* Cb = C + (size_t)(bm * BM) * Nn + bn * BN;
#pragma unroll
  for (int i = 0; i < TM; i++)
#pragma unroll
    for (int j = 0; j < TN; j++)
      Cb[(size_t)(ty + i * 16) * Nn + tx + j * 16] = acc[i][j];
}

// ---------------------------------------------------------------- rope
__global__ __launch_bounds__(256) void k_rope(float* __restrict__ Q, float* __restrict__ Kb) {
  int idx = blockIdx.x * 256 + threadIdx.x;   // s*256 + h*16 + j
  int s = idx >> 8;
  int r = idx & 255; int h = r >> 4; int j = r & 15;
  float inv = expf(-logf(10000.f) * (float)j / 16.f);
  float ang = (float)s * inv;
  float c = cosf(ang), sn = sinf(ang);
  size_t base = (size_t)s * DIM + h * HDIM;
  float x1 = Q[base + j], x2 = Q[base + 16 + j];
  Q[base + j] = x1 * c - x2 * sn; Q[base + 16 + j] = x1 * sn + x2 * c;
  x1 = Kb[base + j]; x2 = Kb[base + 16 + j];
  Kb[base + j] = x1 * c - x2 * sn; Kb[base + 16 + j] = x1 * sn + x2 * c;
}

// ---------------------------------------------------------------- attention
// one block per (q, h); scores for all keys live in LDS
__global__ __launch_bounds__(256) void k_attn(const float* __restrict__ Q,
                                              const float* __restrict__ Kb,
                                              const float* __restrict__ V,
                                              float* __restrict__ O) {
  int q = blockIdx.x, h = blockIdx.y, tid = threadIdx.x, lane = tid & 63, wid = tid >> 6;
  __shared__ __align__(16) float qv[HDIM];
  __shared__ float sc[S_LEN];
  __shared__ float wred[4];
  __shared__ float osum[4][HDIM];
  if (tid < HDIM) qv[tid] = Q[(size_t)q * DIM + h * HDIM + tid];
  __syncthreads();
  float mx = -1e30f;
  for (int k = tid; k <= q; k += 256) {
    const float4* kr = (const float4*)(Kb + (size_t)k * DIM + h * HDIM);
    float dt = 0.f;
#pragma unroll
    for (int d4 = 0; d4 < 16; d4++) {
      float4 kv = kr[d4];
      dt += qv[d4*4+0]*kv.x + qv[d4*4+1]*kv.y + qv[d4*4+2]*kv.z + qv[d4*4+3]*kv.w;
    }
    dt *= 0.125f;                 // 1/sqrt(64)
    sc[k] = dt; mx = fmaxf(mx, dt);
  }
  mx = waveReduceMax(mx);
  if (lane == 0) wred[wid] = mx;
  __syncthreads();
  float gm = fmaxf(fmaxf(wred[0], wred[1]), fmaxf(wred[2], wred[3]));
  __syncthreads();
  float ls = 0.f;
  for (int k = tid; k <= q; k += 256) { float e = expf(sc[k] - gm); sc[k] = e; ls += e; }
  ls = waveReduceSum(ls);
  if (lane == 0) wred[wid] = ls;
  __syncthreads();
  float gs = wred[0] + wred[1] + wred[2] + wred[3];
  int d = tid & 63, part = tid >> 6;
  float acc = 0.f;
  for (int k = part; k <= q; k += 4) acc += sc[k] * V[(size_t)k * DIM + h * HDIM + d];
  osum[part][d] = acc;
  __syncthreads();
  if (tid < HDIM)
    O[(size_t)q * DIM + h * HDIM + tid] =
        (osum[0][tid] + osum[1][tid] + osum[2][tid] + osum[3][tid]) / gs;
}

// --------------------------------------------- hyper-connection update
// xo[s,m,d] = post[s,m]*(a[+a2])[s,d] + sum_n M[s,n,m]*x[s,n,d]   (in-place safe)
__global__ __launch_bounds__(256) void k_hcupd(const float* __restrict__ x,
                                               const float* __restrict__ a,
                                               const float* __restrict__ a2,
                                               const float* __restrict__ post,
                                               const float* __restrict__ Mb,
                                               float* __restrict__ xo) {
  int s = blockIdx.x, tid = threadIdx.x;
  __shared__ float Ms[16];
  if (tid < 16) Ms[tid] = Mb[s * 16 + tid];
  __syncthreads();
  float p0 = post[s*4+0], p1 = post[s*4+1], p2 = post[s*4+2], p3 = post[s*4+3];
  const float* xr = x + (size_t)s * NSTR * DIM;
  float* xw = xo + (size_t)s * NSTR * DIM;
  for (int d = tid; d < DIM; d += 256) {
    float av = a[(size_t)s * DIM + d];
    if (a2) av += a2[(size_t)s * DIM + d];
    float x0 = xr[d], x1 = xr[DIM+d], x2 = xr[2*DIM+d], x3 = xr[3*DIM+d];
    float o0 = p0*av + Ms[0]*x0 + Ms[4]*x1 + Ms[8]*x2  + Ms[12]*x3;
    float o1 = p1*av + Ms[1]*x0 + Ms[5]*x1 + Ms[9]*x2  + Ms[13]*x3;
    float o2 = p2*av + Ms[2]*x0 + Ms[6]*x1 + Ms[10]*x2 + Ms[14]*x3;
    float o3 = p3*av + Ms[3]*x0 + Ms[7]*x1 + Ms[11]*x2 + Ms[15]*x3;
    xw[d] = o0; xw[DIM+d] = o1; xw[2*DIM+d] = o2; xw[3*DIM+d] = o3;
  }
}

// ---------------------------------------------------------------- gating
__global__ __launch_bounds__(256) void k_gate(const float* __restrict__ hb,
                                              const float* __restrict__ gw,
                                              float* __restrict__ gates) {
  int t = blockIdx.x, tid = threadIdx.x;
  int e = tid >> 5, l32 = tid & 31;
  __shared__ float ge[8];
  const float* xr = hb + (size_t)t * DIM;
  const float* wr = gw + (size_t)e * DIM;
  float a = 0.f;
  for (int d = l32; d < DIM; d += 32) a += xr[d] * wr[d];
  for (int off = 16; off > 0; off >>= 1) a += __shfl_down(a, off, 32);
  if (l32 == 0) ge[e] = a;
  __syncthreads();
  if (tid < 8) {
    float v = ge[tid];
    float sp = fmaxf(v, 0.f) + log1pf(expf(-fabsf(v)));  // softplus, stable
    gates[t * 8 + tid] = sqrtf(sp);
  }
}

__global__ __launch_bounds__(256) void k_route(const float* __restrict__ gates,
                                               const int* __restrict__ ids,
                                               const int* __restrict__ tid2eid,
                                               int is_hash,
                                               int* __restrict__ idxb,
                                               float* __restrict__ wgtb) {
  int t = blockIdx.x * 256 + threadIdx.x;
  if (t >= S_LEN) return;
  int e0, e1;
  if (is_hash) {
    int id = ids[t];
    e0 = tid2eid[id * 2]; e1 = tid2eid[id * 2 + 1];
  } else {
    const float* g = gates + t * 8;
    e0 = 0; float b0 = g[0];
    for (int e = 1; e < 8; e++) if (g[e] > b0) { b0 = g[e]; e0 = e; }
    e1 = (e0 == 0) ? 1 : 0; float b1 = g[e1];
    for (int e = 0; e < 8; e++) {
      if (e == e0) continue;
      if (g[e] > b1) { b1 = g[e]; e1 = e; }
    }
  }
  float w0 = gates[t * 8 + e0], w1 = gates[t * 8 + e1];
  float f = 2.5f / (w0 + w1 + 1e-20f);
  idxb[t * 2] = e0; idxb[t * 2 + 1] = e1;
  wgtb[t * 2] = w0 * f; wgtb[t * 2 + 1] = w1 * f;
}

// ------------------------------------------- expert FFN (sparse, per slot)
__global__ __launch_bounds__(256) void k_expert_gu(const float* __restrict__ hb,
                                                   const int* __restrict__ idxb,
                                                   const float* __restrict__ wg,
                                                   const float* __restrict__ wu,
                                                   float* __restrict__ eact) {
  int bi = blockIdx.x; int t = bi >> 1, slot = bi & 1;
  int tid = threadIdx.x;
  int e = idxb[t * 2 + slot];
  __shared__ __align__(16) float xs[DIM];
  for (int i = tid; i < DIM / 4; i += 256)
    ((float4*)xs)[i] = ((const float4*)(hb + (size_t)t * DIM))[i];
  __syncthreads();
  const float* wgb = wg + (size_t)e * DIM * FF;
  const float* wub = wu + (size_t)e * DIM * FF;
  float g0 = 0, g1 = 0, u0 = 0, u1 = 0;
  int f0 = tid, f1 = tid + 256;
  for (int d = 0; d < DIM; d++) {
    float xv = xs[d];
    const float* wgr = wgb + (size_t)d * FF;
    const float* wur = wub + (size_t)d * FF;
    g0 += xv * wgr[f0]; g1 += xv * wgr[f1];
    u0 += xv * wur[f0]; u1 += xv * wur[f1];
  }
  eact[((size_t)t * 2 + slot) * FF + f0] = siluf(g0) * u0;
  eact[((size_t)t * 2 + slot) * FF + f1] = siluf(g1) * u1;
}

__global__ __launch_bounds__(256) void k_expert_down(const float* __restrict__ eact,
                                                     const int* __restrict__ idxb,
                                                     const float* __restrict__ wgtb,
                                                     const float* __restrict__ wd,
                                                     float* __restrict__ routed) {
  int t = blockIdx.x, tid = threadIdx.x;
  __shared__ __align__(16) float as2[2 * FF];
  for (int i = tid; i < 2 * FF / 4; i += 256)
    ((float4*)as2)[i] = ((const float4*)(eact + (size_t)t * 2 * FF))[i];
  __syncthreads();
  float acc0 = 0, acc1 = 0, acc2 = 0, acc3 = 0;
  for (int slot = 0; slot < 2; slot++) {
    int e = idxb[t * 2 + slot];
    float w = wgtb[t * 2 + slot];
    const float* wdb = wd + (size_t)e * FF * DIM;
    for (int f = 0; f < FF; f++) {
      float av = as2[slot * FF + f] * w;
      const float* wr = wdb + (size_t)f * DIM;
      acc0 += av * wr[tid];       acc1 += av * wr[tid + 256];
      acc2 += av * wr[tid + 512]; acc3 += av * wr[tid + 768];
    }
  }
  float* rr = routed + (size_t)t * DIM;
  rr[tid] = acc0; rr[tid + 256] = acc1; rr[tid + 512] = acc2; rr[tid + 768] = acc3;
}

__global__ __launch_bounds__(256) void k_silu_mul(const float* __restrict__ g,
                                                  const float* __restrict__ u,
                                                  float* __restrict__ o, int n) {
  int i = blockIdx.x * 256 + threadIdx.x;
  if (i < n) { float gv = g[i]; o[i] = siluf(gv) * u[i]; }
}

// =======================================================================
extern "C" void kernel_launch(void* const* d_in, const int* in_sizes, int n_in,
                              void* d_out, int out_size, void* d_ws, size_t ws_size,
                              hipStream_t stream) {
  (void)in_sizes; (void)n_in; (void)out_size; (void)ws_size;
  const int*   ids      = (const int*)d_in[0];
  const int*   tid2eid  = (const int*)d_in[1];
  const float* embed    = (const float*)d_in[2];
  const float* attn_hc_w= (const float*)d_in[3];
  const float* attn_hc_b= (const float*)d_in[4];
  const float* ffn_hc_w = (const float*)d_in[5];
  const float* ffn_hc_b = (const float*)d_in[6];
  const float* ln1      = (const float*)d_in[7];
  const float* ln2      = (const float*)d_in[8];
  const float* wq       = (const float*)d_in[9];
  const float* wk       = (const float*)d_in[10];
  const float* wv       = (const float*)d_in[11];
  const float* wo       = (const float*)d_in[12];
  const float* gate_w   = (const float*)d_in[13];
  const float* wg_e     = (const float*)d_in[14];
  const float* wu_e     = (const float*)d_in[15];
  const float* wd_e     = (const float*)d_in[16];
  const float* wg_s     = (const float*)d_in[17];
  const float* wu_s     = (const float*)d_in[18];
  const float* wd_s     = (const float*)d_in[19];
  const float* head_w   = (const float*)d_in[20];
  const float* head_b   = (const float*)d_in[21];
  const float* fnw      = (const float*)d_in[22];
  const float* lm_head  = (const float*)d_in[23];
  float* out = (float*)d_out;

  float* ws = (float*)d_ws;
  size_t o = 0;
  float* X    = ws + o; o += (size_t)S_LEN * NSTR * DIM;   // state, updated in place
  float* HBUF = ws + o; o += (size_t)S_LEN * DIM;
  float* T1   = ws + o; o += (size_t)S_LEN * DIM;          // q / expert act
  float* T2   = ws + o; o += (size_t)S_LEN * DIM;          // k / routed
  float* T3   = ws + o; o += (size_t)S_LEN * DIM;          // v / gs,acts
  float* T4   = ws + o; o += (size_t)S_LEN * DIM;          // o / us,shared
  float* PRE  = ws + o; o += (size_t)S_LEN * 4;
  float* POST = ws + o; o += (size_t)S_LEN * 4;
  float* MM   = ws + o; o += (size_t)S_LEN * 16;
  float* GATES= ws + o; o += (size_t)S_LEN * 8;
  float* WGT  = ws + o; o += (size_t)S_LEN * 2;
  int*   IDX  = (int*)(ws + o); o += (size_t)S_LEN * 2;

  dim3 g128(DIM / 128, S_LEN / 128);
  dim3 gattn(S_LEN, NHEAD);

  k_embed<<<S_LEN, 256, 0, stream>>>(ids, embed, X);

  for (int l = 0; l < 2; l++) {
    // ---- attention sub-block
    k_hc<NCC, true><<<S_LEN, 256, 0, stream>>>(X, attn_hc_w + (size_t)l * NSTR * DIM * NCC,
                                               attn_hc_b + l * NCC, PRE, POST, MM);
    k_coll<<<S_LEN, 256, 0, stream>>>(X, PRE, ln1 + (size_t)l * DIM, HBUF);
    sgemm<128,128><<<g128, 256, 0, stream>>>(HBUF, wq + (size_t)l * DIM * DIM, T1, S_LEN, DIM, DIM);
    sgemm<128,128><<<g128, 256, 0, stream>>>(HBUF, wk + (size_t)l * DIM * DIM, T2, S_LEN, DIM, DIM);
    sgemm<128,128><<<g128, 256, 0, stream>>>(HBUF, wv + (size_t)l * DIM * DIM, T3, S_LEN, DIM, DIM);
    k_rope<<<S_LEN, 256, 0, stream>>>(T1, T2);
    k_attn<<<gattn, 256, 0, stream>>>(T1, T2, T3, T4);
    sgemm<128,128><<<g128, 256, 0, stream>>>(T4, wo + (size_t)l * DIM * DIM, HBUF, S_LEN, DIM, DIM);
    k_hcupd<<<S_LEN, 256, 0, stream>>>(X, HBUF, nullptr, POST, MM, X);

    // ---- MoE sub-block
    k_hc<NCC, true><<<S_LEN, 256, 0, stream>>>(X, ffn_hc_w + (size_t)l * NSTR * DIM * NCC,
                                               ffn_hc_b + l * NCC, PRE, POST, MM);
    k_coll<<<S_LEN, 256, 0, stream>>>(X, PRE, ln2 + (size_t)l * DIM, HBUF);
    k_gate<<<S_LEN, 256, 0, stream>>>(HBUF, gate_w + (size_t)l * NEXP * DIM, GATES);
    k_route<<<S_LEN / 256, 256, 0, stream>>>(GATES, ids, tid2eid, (l == 0) ? 1 : 0, IDX, WGT);
    k_expert_gu<<<S_LEN * 2, 256, 0, stream>>>(HBUF, IDX,
                                               wg_e + (size_t)l * NEXP * DIM * FF,
                                               wu_e + (size_t)l * NEXP * DIM * FF, T1);
    k_expert_down<<<S_LEN, 256, 0, stream>>>(T1, IDX, WGT,
                                             wd_e + (size_t)l * NEXP * FF * DIM, T2);
    dim3 g64a(FF / 64, S_LEN / 64);
    sgemm<64,64><<<g64a, 256, 0, stream>>>(HBUF, wg_s + (size_t)l * DIM * FF, T3, S_LEN, DIM, FF);
    sgemm<64,64><<<g64a, 256, 0, stream>>>(HBUF, wu_s + (size_t)l * DIM * FF, T4, S_LEN, DIM, FF);
    k_silu_mul<<<(S_LEN * FF) / 256, 256, 0, stream>>>(T3, T4, T3, S_LEN * FF);
    dim3 g64b(DIM / 64, S_LEN / 64);
    sgemm<64,64><<<g64b, 256, 0, stream>>>(T3, wd_s + (size_t)l * FF * DIM, T4, S_LEN, FF, DIM);
    k_hcupd<<<S_LEN, 256, 0, stream>>>(X, T2, T4, POST, MM, X);
  }

  // ---- final head
  k_hc<4, false><<<S_LEN, 256, 0, stream>>>(X, head_w, head_b, PRE, nullptr, nullptr);
  k_coll<<<S_LEN, 256, 0, stream>>>(X, PRE, fnw, HBUF);
  dim3 gout(VOC / 128, S_LEN / 128);
  sgemm<128,128><<<gout, 256, 0, stream>>>(HBUF, lm_head, out, S_LEN, DIM, VOC);
}